// Round 1
// baseline (3328.845 us; speedup 1.0000x reference)
//
#include <hip/hip_runtime.h>

#define N1 32768
#define NP1 512
#define NS1 32
#define N2 512
#define NP2 256
#define NS2 64

// ---- exact-rounding helpers: replicate reference op-by-op (NO fma/contract) ----
__device__ __forceinline__ float fadd(float a, float b){ return __fadd_rn(a,b); }
__device__ __forceinline__ float fmul(float a, float b){ return __fmul_rn(a,b); }
__device__ __forceinline__ float fsub(float a, float b){ return __fsub_rn(a,b); }

// sum((p-c)^2) as ((dx*dx + dy*dy) + dz*dz), left-to-right, no contraction
__device__ __forceinline__ float dist3(float px,float py,float pz,float cx,float cy,float cz){
    float dx = fsub(px,cx), dy = fsub(py,cy), dz = fsub(pz,cz);
    return fadd(fadd(fmul(dx,dx), fmul(dy,dy)), fmul(dz,dz));
}
__device__ __forceinline__ float sumsq3(float x,float y,float z){
    return fadd(fadd(fmul(x,x), fmul(y,y)), fmul(z,z));
}
__device__ __forceinline__ float dot3(float ax,float ay,float az,float bx,float by,float bz){
    return fadd(fadd(fmul(ax,bx), fmul(ay,by)), fmul(az,bz));
}

// =====================  FPS over 32768 pts, 512 picks  =====================
// 1 block per batch. 512 thr * 64 pts. coords in VGPRs (192), dist split:
// 34 in VGPRs + 30 in LDS (61440 B) to stay under 256 VGPR / 64 KB LDS caps.
#define FPS1_T 512
#define FPS1_P 64
#define FPS1_DR 34
#define FPS1_DL 30

__global__ __launch_bounds__(FPS1_T) void fps1_kernel(const float* __restrict__ xyz,
                                                      float* __restrict__ new_xyz1)
{
    const int b = blockIdx.x;
    const int t = threadIdx.x;
    const float* xb = xyz + (size_t)b * 6 * N1;

    __shared__ float ddl[FPS1_DL * FPS1_T];
    __shared__ float swv[8];
    __shared__ int   swi[8];
    __shared__ int   winner;

    float px[FPS1_P], py[FPS1_P], pz[FPS1_P];
    float ddr[FPS1_DR];

#pragma unroll
    for (int j = 0; j < FPS1_P; ++j) {
        int n = t + j * FPS1_T;
        px[j] = xb[n];
        py[j] = xb[N1 + n];
        pz[j] = xb[2*N1 + n];
    }
#pragma unroll
    for (int j = 0; j < FPS1_DR; ++j) ddr[j] = 1e10f;
    for (int j = 0; j < FPS1_DL; ++j) ddl[j*FPS1_T + t] = 1e10f;
    __syncthreads();

    const int lane = t & 63;
    const int wid  = t >> 6;
    int cur = 0;  // reference: first pick is index 0

    for (int s = 0; s < NP1; ++s) {
        // centroid coords (wave-uniform address, one cacheline broadcast)
        float cx = xb[cur], cy = xb[N1+cur], cz = xb[2*N1+cur];
        if (t == 0) {
            float* o = new_xyz1 + ((size_t)b*NP1 + s)*3;
            o[0]=cx; o[1]=cy; o[2]=cz;
        }
        float bv = -1.0f; int bi = 0x7fffffff;
#pragma unroll
        for (int j = 0; j < FPS1_DR; ++j) {
            float d  = dist3(px[j],py[j],pz[j],cx,cy,cz);
            float nd = fminf(ddr[j], d);
            ddr[j] = nd;
            int n = t + j*FPS1_T;
            if (nd > bv) { bv = nd; bi = n; }   // ascending n -> first-max kept
        }
#pragma unroll
        for (int j = FPS1_DR; j < FPS1_P; ++j) {
            int sl = (j - FPS1_DR)*FPS1_T + t;
            float d  = dist3(px[j],py[j],pz[j],cx,cy,cz);
            float nd = fminf(ddl[sl], d);
            ddl[sl] = nd;
            int n = t + j*FPS1_T;
            if (nd > bv) { bv = nd; bi = n; }
        }
        // wave butterfly argmax, tie -> smaller index (jnp.argmax = first)
#pragma unroll
        for (int m = 1; m < 64; m <<= 1) {
            float ov = __shfl_xor(bv, m, 64);
            int   oi = __shfl_xor(bi, m, 64);
            if (ov > bv || (ov == bv && oi < bi)) { bv = ov; bi = oi; }
        }
        if (lane == 0) { swv[wid] = bv; swi[wid] = bi; }
        __syncthreads();
        if (wid == 0) {
            float v2 = (lane < 8) ? swv[lane] : -1.0f;
            int   i2 = (lane < 8) ? swi[lane] : 0x7fffffff;
#pragma unroll
            for (int m = 1; m < 8; m <<= 1) {
                float ov = __shfl_xor(v2, m, 64);
                int   oi = __shfl_xor(i2, m, 64);
                if (ov > v2 || (ov == v2 && oi < i2)) { v2 = ov; i2 = oi; }
            }
            if (lane == 0) winner = i2;
        }
        __syncthreads();
        cur = winner;
    }
}

// =====================  FPS over 512 pts, 256 picks: 1 wave/batch  =====================
__global__ __launch_bounds__(64) void fps2_kernel(const float* __restrict__ new_xyz1,
                                                  float* __restrict__ new_xyz2,
                                                  float* __restrict__ out0)
{
    const int b = blockIdx.x;
    const int t = threadIdx.x;
    __shared__ float c3[N2*3];
    const float* src = new_xyz1 + (size_t)b*N2*3;
    for (int e = t; e < N2*3; e += 64) c3[e] = src[e];
    __syncthreads();

    float px[8], py[8], pz[8], dd[8];
#pragma unroll
    for (int j = 0; j < 8; ++j) {
        int n = t + j*64;
        px[j] = c3[n*3]; py[j] = c3[n*3+1]; pz[j] = c3[n*3+2];
        dd[j] = 1e10f;
    }
    int cur = 0;
    for (int s = 0; s < NP2; ++s) {
        float cx = c3[cur*3], cy = c3[cur*3+1], cz = c3[cur*3+2];
        if (t == 0) {
            float* o = new_xyz2 + ((size_t)b*NP2 + s)*3;
            o[0]=cx; o[1]=cy; o[2]=cz;
            out0[b*3*NP2 + s]         = cx;   // l2_xyz transposed (8,3,256)
            out0[b*3*NP2 + NP2 + s]   = cy;
            out0[b*3*NP2 + 2*NP2 + s] = cz;
        }
        float bv = -1.0f; int bi = 0x7fffffff;
#pragma unroll
        for (int j = 0; j < 8; ++j) {
            float d  = dist3(px[j],py[j],pz[j],cx,cy,cz);
            float nd = fminf(dd[j], d);
            dd[j] = nd;
            int n = t + j*64;
            if (nd > bv) { bv = nd; bi = n; }
        }
#pragma unroll
        for (int m = 1; m < 64; m <<= 1) {
            float ov = __shfl_xor(bv, m, 64);
            int   oi = __shfl_xor(bi, m, 64);
            if (ov > bv || (ov == bv && oi < bi)) { bv = ov; bi = oi; }
        }
        cur = bi;
    }
}

// =====================  ball query 1: 1 wave per centroid  =====================
__global__ __launch_bounds__(64) void ball1_kernel(const float* __restrict__ xyz,
                                                   const float* __restrict__ new_xyz1,
                                                   int* __restrict__ idx1, float r2)
{
    const int s = blockIdx.x, b = blockIdx.y;
    const int lane = threadIdx.x;
    const float* xb = xyz + (size_t)b*6*N1;
    const float* cp = new_xyz1 + ((size_t)b*NP1 + s)*3;
    float cx = cp[0], cy = cp[1], cz = cp[2];
    float snew = sumsq3(cx,cy,cz);
    int* out = idx1 + ((size_t)b*NP1 + s)*NS1;
    int cnt = 0, first = 0;
    for (int ch = 0; ch < N1/64; ++ch) {
        int n = ch*64 + lane;
        float x = xb[n], y = xb[N1+n], z = xb[2*N1+n];
        float sx  = sumsq3(x,y,z);
        float dt  = dot3(cx,cy,cz,x,y,z);
        float sqr = fsub(fadd(snew, sx), fmul(2.0f, dt));   // (|c|^2+|p|^2) - 2*dot
        bool inb = !(sqr > r2);
        unsigned long long mask = __ballot(inb);
        if (mask) {
            if (cnt == 0) first = ch*64 + (int)(__ffsll((unsigned long long)mask) - 1);
            if (inb) {
                int pos = cnt + (int)__popcll(mask & ((1ull << lane) - 1ull));
                if (pos < NS1) out[pos] = n;
            }
            cnt += (int)__popcll(mask);
            if (cnt >= NS1) break;
        }
    }
    int c = cnt < NS1 ? cnt : NS1;
    if (lane < NS1 && lane >= c) out[lane] = first;
}

// =====================  ball query 2  =====================
__global__ __launch_bounds__(64) void ball2_kernel(const float* __restrict__ new_xyz1,
                                                   const float* __restrict__ new_xyz2,
                                                   int* __restrict__ idx2, float r2)
{
    const int s = blockIdx.x, b = blockIdx.y;
    const int lane = threadIdx.x;
    const float* pb = new_xyz1 + (size_t)b*N2*3;
    const float* cp = new_xyz2 + ((size_t)b*NP2 + s)*3;
    float cx = cp[0], cy = cp[1], cz = cp[2];
    float snew = sumsq3(cx,cy,cz);
    int* out = idx2 + ((size_t)b*NP2 + s)*NS2;
    int cnt = 0, first = 0;
    for (int ch = 0; ch < N2/64; ++ch) {
        int n = ch*64 + lane;
        float x = pb[n*3], y = pb[n*3+1], z = pb[n*3+2];
        float sx  = sumsq3(x,y,z);
        float dt  = dot3(cx,cy,cz,x,y,z);
        float sqr = fsub(fadd(snew, sx), fmul(2.0f, dt));
        bool inb = !(sqr > r2);
        unsigned long long mask = __ballot(inb);
        if (mask) {
            if (cnt == 0) first = ch*64 + (int)(__ffsll((unsigned long long)mask) - 1);
            if (inb) {
                int pos = cnt + (int)__popcll(mask & ((1ull << lane) - 1ull));
                if (pos < NS2) out[pos] = n;
            }
            cnt += (int)__popcll(mask);
            if (cnt >= NS2) break;
        }
    }
    int c = cnt < NS2 ? cnt : NS2;
    if (lane >= c) out[lane] = first;
}

// =====================  SA1 MLP (6->64->64->128) + maxpool over 32  =====================
__global__ __launch_bounds__(256) void mlp1_kernel(const float* __restrict__ xyz,
    const float* __restrict__ new_xyz1, const int* __restrict__ idx1,
    const float* __restrict__ W1, const float* __restrict__ B1,
    const float* __restrict__ W2, const float* __restrict__ B2,
    const float* __restrict__ W3, const float* __restrict__ B3,
    float* __restrict__ l1_points)
{
    const int s = blockIdx.x, b = blockIdx.y;
    const int t = threadIdx.x;
    const float* xb = xyz + (size_t)b*6*N1;
    __shared__ float inb_[NS1][6];
    __shared__ float h1_[NS1][64];
    __shared__ float h2_[NS1][64];
    __shared__ float red_[2][128];
    __shared__ int sidx[NS1];

    const float* cp = new_xyz1 + ((size_t)b*NP1 + s)*3;
    float c0 = cp[0], c1 = cp[1], c2 = cp[2];
    if (t < NS1) sidx[t] = idx1[((size_t)b*NP1+s)*NS1 + t];
    __syncthreads();
    if (t < NS1*6) {
        int k = t / 6, c = t % 6;
        int n = sidx[k];
        float v = xb[(size_t)c*N1 + n];
        if (c == 0) v -= c0; else if (c == 1) v -= c1; else if (c == 2) v -= c2;
        inb_[k][c] = v;
    }
    __syncthreads();
    {   // L1
        int o = t & 63, kg = t >> 6;
        float w[6];
#pragma unroll
        for (int c = 0; c < 6; ++c) w[c] = W1[o*6+c];
        float bias = B1[o];
#pragma unroll
        for (int kk = 0; kk < 8; ++kk) {
            int k = kg*8 + kk;
            float a = 0.f;
#pragma unroll
            for (int c = 0; c < 6; ++c) a = fmaf(inb_[k][c], w[c], a);
            h1_[k][o] = fmaxf(a + bias, 0.f);
        }
    }
    __syncthreads();
    {   // L2
        int o = t & 63, kg = t >> 6;
        float acc[8] = {};
        for (int ch = 0; ch < 8; ++ch) {
            float w[8];
#pragma unroll
            for (int j = 0; j < 8; ++j) w[j] = W2[o*64 + ch*8 + j];
#pragma unroll
            for (int kk = 0; kk < 8; ++kk) {
                int k = kg*8+kk;
#pragma unroll
                for (int j = 0; j < 8; ++j) acc[kk] = fmaf(h1_[k][ch*8+j], w[j], acc[kk]);
            }
        }
        float bias = B2[o];
#pragma unroll
        for (int kk = 0; kk < 8; ++kk) h2_[kg*8+kk][o] = fmaxf(acc[kk] + bias, 0.f);
    }
    __syncthreads();
    {   // L3 + max over samples
        int o = t & 127, kg = t >> 7;
        float acc[16] = {};
        for (int ch = 0; ch < 8; ++ch) {
            float w[8];
#pragma unroll
            for (int j = 0; j < 8; ++j) w[j] = W3[o*64 + ch*8 + j];
#pragma unroll
            for (int kk = 0; kk < 16; ++kk) {
                int k = kg*16+kk;
#pragma unroll
                for (int j = 0; j < 8; ++j) acc[kk] = fmaf(h2_[k][ch*8+j], w[j], acc[kk]);
            }
        }
        float bias = B3[o];
        float m = -1e30f;
#pragma unroll
        for (int kk = 0; kk < 16; ++kk) m = fmaxf(m, fmaxf(acc[kk] + bias, 0.f));
        red_[kg][o] = m;
    }
    __syncthreads();
    if (t < 128) {
        float m = fmaxf(red_[0][t], red_[1][t]);
        l1_points[((size_t)b*NP1+s)*128 + t] = m;   // (b, n, 128) layout
    }
}

// =====================  SA2 MLP (131->128->128->285) + maxpool over 64  =====================
// two sample-halves to stay < 64 KB LDS
__global__ __launch_bounds__(256) void mlp2_kernel(
    const float* __restrict__ new_xyz1, const float* __restrict__ l1_points,
    const float* __restrict__ new_xyz2, const int* __restrict__ idx2,
    const float* __restrict__ W1, const float* __restrict__ B1,
    const float* __restrict__ W2, const float* __restrict__ B2,
    const float* __restrict__ W3, const float* __restrict__ B3,
    float* __restrict__ out1)
{
    const int s = blockIdx.x, b = blockIdx.y;
    const int t = threadIdx.x;
    __shared__ float inb_[32][131];
    __shared__ float h1_[32][128];
    __shared__ float h2_[32][128];
    __shared__ int sidx[NS2];

    const float* cp = new_xyz2 + ((size_t)b*NP2+s)*3;
    float c0=cp[0], c1=cp[1], c2=cp[2];
    if (t < NS2) sidx[t] = idx2[((size_t)b*NP2+s)*NS2 + t];

    float vmax0 = -1e30f, vmax1 = -1e30f;

    for (int half = 0; half < 2; ++half) {
        __syncthreads();
        for (int e = t; e < 32*131; e += 256) {
            int kk = e / 131, c = e % 131;
            int n = sidx[half*32 + kk];
            float v;
            if (c < 3) v = new_xyz1[((size_t)b*N2 + n)*3 + c] - (c==0?c0:(c==1?c1:c2));
            else       v = l1_points[((size_t)b*N2 + n)*128 + (c-3)];
            inb_[kk][c] = v;
        }
        __syncthreads();
        {   // L1: 131 -> 128
            int o = t & 127, kg = t >> 7;
            float acc[16] = {};
            for (int ch = 0; ch < 16; ++ch) {
                float w[8];
#pragma unroll
                for (int j=0;j<8;++j) w[j] = W1[o*131 + ch*8 + j];
#pragma unroll
                for (int kk=0; kk<16; ++kk) {
                    int k = kg*16+kk;
#pragma unroll
                    for (int j=0;j<8;++j) acc[kk] = fmaf(inb_[k][ch*8+j], w[j], acc[kk]);
                }
            }
            float wr0=W1[o*131+128], wr1=W1[o*131+129], wr2=W1[o*131+130];
#pragma unroll
            for (int kk=0;kk<16;++kk) {
                int k = kg*16+kk;
                acc[kk] = fmaf(inb_[k][128], wr0, acc[kk]);
                acc[kk] = fmaf(inb_[k][129], wr1, acc[kk]);
                acc[kk] = fmaf(inb_[k][130], wr2, acc[kk]);
            }
            float bias = B1[o];
#pragma unroll
            for (int kk=0;kk<16;++kk) h1_[kg*16+kk][o] = fmaxf(acc[kk]+bias, 0.f);
        }
        __syncthreads();
        {   // L2: 128 -> 128
            int o = t & 127, kg = t >> 7;
            float acc[16] = {};
            for (int ch = 0; ch < 16; ++ch) {
                float w[8];
#pragma unroll
                for (int j=0;j<8;++j) w[j] = W2[o*128 + ch*8 + j];
#pragma unroll
                for (int kk=0; kk<16; ++kk) {
                    int k = kg*16+kk;
#pragma unroll
                    for (int j=0;j<8;++j) acc[kk] = fmaf(h1_[k][ch*8+j], w[j], acc[kk]);
                }
            }
            float bias = B2[o];
#pragma unroll
            for (int kk=0;kk<16;++kk) h2_[kg*16+kk][o] = fmaxf(acc[kk]+bias, 0.f);
        }
        __syncthreads();
        // L3: 128 -> 285, fold max over this half's 32 samples
        {
            int o = t;
            if (o < 285) {
                float acc[32] = {};
                for (int ch = 0; ch < 16; ++ch) {
                    float w[8];
#pragma unroll
                    for (int j=0;j<8;++j) w[j] = W3[o*128 + ch*8 + j];
#pragma unroll
                    for (int kk=0; kk<32; ++kk) {
#pragma unroll
                        for (int j=0;j<8;++j) acc[kk] = fmaf(h2_[kk][ch*8+j], w[j], acc[kk]);
                    }
                }
                float bias = B3[o];
                float m = vmax0;
#pragma unroll
                for (int kk=0;kk<32;++kk) m = fmaxf(m, fmaxf(acc[kk]+bias, 0.f));
                vmax0 = m;
            }
            o = t + 256;
            if (o < 285) {
                float acc[32] = {};
                for (int ch = 0; ch < 16; ++ch) {
                    float w[8];
#pragma unroll
                    for (int j=0;j<8;++j) w[j] = W3[o*128 + ch*8 + j];
#pragma unroll
                    for (int kk=0; kk<32; ++kk) {
#pragma unroll
                        for (int j=0;j<8;++j) acc[kk] = fmaf(h2_[kk][ch*8+j], w[j], acc[kk]);
                    }
                }
                float bias = B3[o];
                float m = vmax1;
#pragma unroll
                for (int kk=0;kk<32;++kk) m = fmaxf(m, fmaxf(acc[kk]+bias, 0.f));
                vmax1 = m;
            }
        }
    }
    if (t < 285)       out1[((size_t)b*NP2+s)*285 + t]       = vmax0;
    if (t + 256 < 285) out1[((size_t)b*NP2+s)*285 + t + 256] = vmax1;
}

extern "C" void kernel_launch(void* const* d_in, const int* in_sizes, int n_in,
                              void* d_out, int out_size, void* d_ws, size_t ws_size,
                              hipStream_t stream)
{
    (void)in_sizes; (void)n_in; (void)out_size; (void)ws_size;
    const float* xyz  = (const float*)d_in[0];
    const float* s1w1 = (const float*)d_in[1];  const float* s1b1 = (const float*)d_in[2];
    const float* s1w2 = (const float*)d_in[3];  const float* s1b2 = (const float*)d_in[4];
    const float* s1w3 = (const float*)d_in[5];  const float* s1b3 = (const float*)d_in[6];
    const float* s2w1 = (const float*)d_in[7];  const float* s2b1 = (const float*)d_in[8];
    const float* s2w2 = (const float*)d_in[9];  const float* s2b2 = (const float*)d_in[10];
    const float* s2w3 = (const float*)d_in[11]; const float* s2b3 = (const float*)d_in[12];

    float* ws        = (float*)d_ws;
    float* new_xyz1  = ws;                  // 8*512*3   = 12288 f
    float* new_xyz2  = ws + 12288;          // 8*256*3   = 6144 f
    float* l1_points = ws + 18432;          // 8*512*128 = 524288 f
    int*   idx1      = (int*)(ws + 542720); // 8*512*32  = 131072 i
    int*   idx2      = idx1 + 131072;       // 8*256*64  = 131072 i

    float* out0 = (float*)d_out;            // (8,3,256)
    float* out1 = out0 + 8*3*256;           // (8,256,285)

    const float r2a = (float)(0.025*0.025);
    const float r2b = (float)(0.05*0.05);

    fps1_kernel <<<dim3(8),      dim3(FPS1_T), 0, stream>>>(xyz, new_xyz1);
    ball1_kernel<<<dim3(NP1, 8), dim3(64),     0, stream>>>(xyz, new_xyz1, idx1, r2a);
    mlp1_kernel <<<dim3(NP1, 8), dim3(256),    0, stream>>>(xyz, new_xyz1, idx1,
                    s1w1,s1b1,s1w2,s1b2,s1w3,s1b3, l1_points);
    fps2_kernel <<<dim3(8),      dim3(64),     0, stream>>>(new_xyz1, new_xyz2, out0);
    ball2_kernel<<<dim3(NP2, 8), dim3(64),     0, stream>>>(new_xyz1, new_xyz2, idx2, r2b);
    mlp2_kernel <<<dim3(NP2, 8), dim3(256),    0, stream>>>(new_xyz1, l1_points, new_xyz2, idx2,
                    s2w1,s2b1,s2w2,s2b2,s2w3,s2b3, out1);
}